// Round 15
// baseline (92.882 us; speedup 1.0000x reference)
//
#include <hip/hip_runtime.h>
#include <hip/hip_bf16.h>

#define B_    32
#define N_    10000
#define G_    256
#define HID_  256
#define EPS_  1e-5f

#define QK_    4               // gene-range quarters
#define QR_    2500            // gene range per quarter
#define QCAP_  640             // per-(g,q) index capacity (mean 50, std 7)

// prep_k grid segmentation
#define TB_W1  2504            // W1 transpose->bf16: 313 x 8 tiles
#define TB_X   313             // x transpose: 32 x 10000
#define TB_W2  64              // W2 transpose (f32): 256 x 256
#define NB_CMP 256             // quartered mask compaction, one block per g
#define PREP_GRID (TB_W1 + TB_X + TB_W2 + NB_CMP)   // 3137

#define NSPB2_ 1024            // sparse blocks: 256 g x 4 q (g=255 slots idle)
#define DKB_   80              // dense chunks (group 255)
#define DCH_   125             // genes per dense chunk
#define K2_GRID (NSPB2_ + DKB_)   // 1104

// ---------------------------------------------------------------------------
// Tiled transpose helpers.
// ---------------------------------------------------------------------------
__device__ inline void transpose_tile(const float* __restrict__ src,
                                      float* __restrict__ dst,
                                      int R, int C, int bx, int by, int t,
                                      float (*tile)[33]) {
    int tx = t & 31, ty = t >> 5;      // 32 x 8
    int c0 = bx * 32, r0 = by * 32;
#pragma unroll
    for (int j = 0; j < 4; ++j) {
        int r = r0 + ty + j * 8, c = c0 + tx;
        if (r < R && c < C) tile[ty + j * 8][tx] = src[(size_t)r * C + c];
    }
    __syncthreads();
#pragma unroll
    for (int j = 0; j < 4; ++j) {
        int c = c0 + ty + j * 8, r = r0 + tx;
        if (r < R && c < C) dst[(size_t)c * R + r] = tile[tx][ty + j * 8];
    }
}

__device__ inline void transpose_tile_bf16(const float* __restrict__ src,
                                           __hip_bfloat16* __restrict__ dst,
                                           int R, int C, int bx, int by, int t,
                                           float (*tile)[33]) {
    int tx = t & 31, ty = t >> 5;      // 32 x 8
    int c0 = bx * 32, r0 = by * 32;
#pragma unroll
    for (int j = 0; j < 4; ++j) {
        int r = r0 + ty + j * 8, c = c0 + tx;
        if (r < R && c < C) tile[ty + j * 8][tx] = src[(size_t)r * C + c];
    }
    __syncthreads();
#pragma unroll
    for (int j = 0; j < 4; ++j) {
        int c = c0 + ty + j * 8, r = r0 + tx;
        if (r < R && c < C)
            dst[(size_t)c * R + r] = __float2bfloat16(tile[tx][ty + j * 8]);
    }
}

// ---------------------------------------------------------------------------
// Fused prep: W1(bf16)/x/W2 transposes + QUARTERED mask compaction.
// idx[(g*4+q)*QCAP_ + pos] holds genes of group g in range [q*2500,(q+1)*2500).
// ---------------------------------------------------------------------------
__global__ __launch_bounds__(256) void prep_k(const float* __restrict__ W1,
                                              const float* __restrict__ x,
                                              const float* __restrict__ W2,
                                              const float* __restrict__ mask,
                                              __hip_bfloat16* __restrict__ w1bf,
                                              float* __restrict__ xt,
                                              float* __restrict__ w2t,
                                              int* __restrict__ cnt4,
                                              unsigned short* __restrict__ idx) {
    __shared__ float tile[32][33];
    __shared__ int c4[QK_];
    int bid = blockIdx.x, t = threadIdx.x;

    if (bid < TB_W1) {
        transpose_tile_bf16(W1, w1bf, HID_, N_, bid % 313, bid / 313, t, tile);
    } else if (bid < TB_W1 + TB_X) {
        transpose_tile(x, xt, B_, N_, bid - TB_W1, 0, t, tile);
    } else if (bid < TB_W1 + TB_X + TB_W2) {
        int b = bid - (TB_W1 + TB_X);
        transpose_tile(W2, w2t, 256, HID_, b % 8, b / 8, t, tile);
    } else {
        int g = bid - (TB_W1 + TB_X + TB_W2);
        if (g == 255) return;              // dense group: no index lists
        if (t < QK_) c4[t] = 0;
        __syncthreads();
        for (int n = t; n < N_; n += 256) {
            if (mask[(size_t)g * N_ + n] != 0.0f) {
                int q = n / QR_;
                int p = atomicAdd(&c4[q], 1);          // LDS atomic only
                if (p < QCAP_)
                    idx[(size_t)(g * QK_ + q) * QCAP_ + p] = (unsigned short)n;
            }
        }
        __syncthreads();
        if (t < QK_) cnt4[g * QK_ + t] = min(c4[t], QCAP_);
    }
}

// ---------------------------------------------------------------------------
// 16 scalar FMAs helper.
// ---------------------------------------------------------------------------
__device__ __forceinline__ float4 bf2f4(uint2 u) {
    float4 w;
    w.x = __uint_as_float(u.x << 16);
    w.y = __uint_as_float(u.x & 0xffff0000u);
    w.z = __uint_as_float(u.y << 16);
    w.w = __uint_as_float(u.y & 0xffff0000u);
    return w;
}

__device__ __forceinline__ void fma16(float4& a0, float4& a1, float4& a2,
                                      float4& a3, float4 w, float4 xv) {
    a0.x = fmaf(xv.x, w.x, a0.x); a0.y = fmaf(xv.x, w.y, a0.y);
    a0.z = fmaf(xv.x, w.z, a0.z); a0.w = fmaf(xv.x, w.w, a0.w);
    a1.x = fmaf(xv.y, w.x, a1.x); a1.y = fmaf(xv.y, w.y, a1.y);
    a1.z = fmaf(xv.y, w.z, a1.z); a1.w = fmaf(xv.y, w.w, a1.w);
    a2.x = fmaf(xv.z, w.x, a2.x); a2.y = fmaf(xv.z, w.y, a2.y);
    a2.z = fmaf(xv.z, w.z, a2.z); a2.w = fmaf(xv.z, w.w, a2.w);
    a3.x = fmaf(xv.w, w.x, a3.x); a3.y = fmaf(xv.w, w.y, a3.y);
    a3.z = fmaf(xv.w, w.z, a3.z); a3.w = fmaf(xv.w, w.w, a3.w);
}

// ---------------------------------------------------------------------------
// GEMM1, quartered: 1104 blocks x 256 thr (4 waves), zero atomics/spins.
//   bid < 1024: (g = bid>>2, q = bid&3) -> genes of g in quarter q -> hpartS.
//               bid%8 = q + 4*(g&1): quarter q lives on XCDs {q, q+4} ->
//               per-XCD-pair W working set = 1.25MB bf16, L2-resident.
//   bid >= 1024: dense chunk c of group 255 (contiguous genes) -> hpartD.
//   tc = t&63: uint2 -> wave's 64 lanes span the full 512B bf16 W-row.
//   tb = t>>6: batches 8tb..8tb+7 (wave-uniform -> xs LDS broadcast).
// ---------------------------------------------------------------------------
__global__ __launch_bounds__(256) void spgemm_k(const uint2* __restrict__ w1bf,
                                                const float4* __restrict__ xt4,
                                                const int* __restrict__ cnt4,
                                                const unsigned short* __restrict__ idx,
                                                float4* __restrict__ hpartS,
                                                float4* __restrict__ hpartD) {
    __shared__ int ns[128];
    __shared__ float4 xs[128][9];      // [gene][b/4] + pad
    const int bid = blockIdx.x, t = threadIdx.x;
    const int tc = t & 63;
    const int tb = t >> 6;

    int kend, gbase = 0;
    bool dense;
    const unsigned short* list = nullptr;
    float4* dst;
    if (bid < NSPB2_) {
        int g = bid >> 2;
        if (g == 255) return;          // dense group handled by chunks
        kend = cnt4[bid];
        list = idx + (size_t)bid * QCAP_;
        dst = hpartS + (size_t)bid * 2048;
        dense = false;
    } else {
        int c = bid - NSPB2_;
        gbase = c * DCH_;
        kend = DCH_;
        dst = hpartD + (size_t)c * 2048;
        dense = true;
    }

    float4 a0 = make_float4(0.f, 0.f, 0.f, 0.f), a1 = a0, a2 = a0, a3 = a0;
    float4 a4 = a0, a5 = a0, a6 = a0, a7 = a0;

    for (int base = 0; base < kend; base += 128) {
        int kn = min(128, kend - base);
        __syncthreads();                           // protect ns/xs reuse
        if (t < kn)
            ns[t] = dense ? (gbase + base + t) : (int)list[base + t];
        __syncthreads();
        for (int i = t; i < kn * 8; i += 256)      // cooperative x gather
            xs[i >> 3][i & 7] = xt4[(size_t)ns[i >> 3] * 8 + (i & 7)];
        __syncthreads();

#pragma unroll 8
        for (int k = 0; k < kn; ++k) {
            float4 wv = bf2f4(w1bf[(size_t)ns[k] * 64 + tc]); // 512B/wave
            float4 xa = xs[k][2 * tb];                        // LDS broadcast
            float4 xb = xs[k][2 * tb + 1];
            fma16(a0, a1, a2, a3, wv, xa);
            fma16(a4, a5, a6, a7, wv, xb);
        }
    }

    dst[(size_t)(8 * tb + 0) * 64 + tc] = a0;
    dst[(size_t)(8 * tb + 1) * 64 + tc] = a1;
    dst[(size_t)(8 * tb + 2) * 64 + tc] = a2;
    dst[(size_t)(8 * tb + 3) * 64 + tc] = a3;
    dst[(size_t)(8 * tb + 4) * 64 + tc] = a4;
    dst[(size_t)(8 * tb + 5) * 64 + tc] = a5;
    dst[(size_t)(8 * tb + 6) * 64 + tc] = a6;
    dst[(size_t)(8 * tb + 7) * 64 + tc] = a7;
}

// ---------------------------------------------------------------------------
// Dense-group reduction: h255[i] = b1 + sum over 80 chunks.
// ---------------------------------------------------------------------------
__global__ __launch_bounds__(256) void reduce_k(const float* __restrict__ hpartD,
                                                const float* __restrict__ b1,
                                                float* __restrict__ h255) {
    int i = blockIdx.x * 256 + threadIdx.x;   // 0..8191
    float s = b1[i & (HID_ - 1)];
#pragma unroll 8
    for (int kb = 0; kb < DKB_; ++kb) s += hpartD[(size_t)kb * (B_ * HID_) + i];
    h255[i] = s;
}

// ---------------------------------------------------------------------------
// Fused (sum 4 quarter partials + b1) -> BN1+ReLU -> GEMM2 -> BN2+ReLU.
// One block per group g, 512 threads. GEMM2: tc=l (full 1KB coalesced w2t
// row per wave), tb=w (rows 4tb..4tb+3 via LDS broadcast) — r9-proven.
// ---------------------------------------------------------------------------
__global__ __launch_bounds__(512) void fused_k(const float4* __restrict__ hpartS,
                                               const float4* __restrict__ h255_4,
                                               const float4* __restrict__ w2t4,
                                               const float4* __restrict__ b1_4,
                                               const float* __restrict__ g1,
                                               const float* __restrict__ be1,
                                               const float4* __restrict__ b2_4,
                                               const float* __restrict__ g2,
                                               const float* __restrict__ be2,
                                               float4* __restrict__ z4) {
    __shared__ float lh[32][260];      // 32 rows(b) x 256(c), pad
    __shared__ float rs[8], rss[8];
    const int g = blockIdx.x, t = threadIdx.x;
    const int w = t >> 6, l = t & 63;
    const int tc = l;                  // float4 z-col: wave spans full row
    const int tb = w;                  // rows 4tb..4tb+3

    // ---- load + sum quarter partials (coalesced), BN1 stats ----
    float s = 0.f, ss = 0.f;
    float4 mine[4];
    const float4* p0 = hpartS + (size_t)g * 4 * 2048;
#pragma unroll
    for (int p = 0; p < 4; ++p) {
        int i = p * 512 + t;                   // 0..2047
        int r = i >> 6, qq = i & 63;
        float4 v;
        if (g < 255) {
            float4 v0 = p0[i], v1 = p0[2048 + i], v2 = p0[4096 + i], v3 = p0[6144 + i];
            float4 bb = b1_4[qq];
            v.x = v0.x + v1.x + v2.x + v3.x + bb.x;
            v.y = v0.y + v1.y + v2.y + v3.y + bb.y;
            v.z = v0.z + v1.z + v2.z + v3.z + bb.z;
            v.w = v0.w + v1.w + v2.w + v3.w + bb.w;
        } else {
            v = h255_4[i];                     // b1 already added by reduce_k
        }
        mine[p] = v;
        *(float4*)&lh[r][4 * qq] = v;
        s  += v.x + v.y + v.z + v.w;
        ss += v.x * v.x + v.y * v.y + v.z * v.z + v.w * v.w;
    }
#pragma unroll
    for (int o = 32; o > 0; o >>= 1) { s += __shfl_down(s, o); ss += __shfl_down(ss, o); }
    if (l == 0) { rs[w] = s; rss[w] = ss; }
    __syncthreads();
    float S = 0.f, SS = 0.f;
#pragma unroll
    for (int j = 0; j < 8; ++j) { S += rs[j]; SS += rss[j]; }
    const float inv = 1.0f / (float)(B_ * HID_);
    float mean = S * inv;
    float var  = SS * inv - mean * mean;       // biased, matches jnp.var
    float sc = g1[g] * rsqrtf(var + EPS_);
    float sh = be1[g] - mean * sc;

    // ---- normalize + ReLU own elements in LDS ----
#pragma unroll
    for (int p = 0; p < 4; ++p) {
        int i = p * 512 + t;
        int r = i >> 6, qq = i & 63;
        float4 v = mine[p];
        v.x = fmaxf(fmaf(v.x, sc, sh), 0.f);
        v.y = fmaxf(fmaf(v.y, sc, sh), 0.f);
        v.z = fmaxf(fmaf(v.z, sc, sh), 0.f);
        v.w = fmaxf(fmaf(v.w, sc, sh), 0.f);
        *(float4*)&lh[r][4 * qq] = v;
    }
    __syncthreads();

    // ---- GEMM2 + BN2 + ReLU ----
    float4 bb2 = b2_4[tc];
    float4 c0 = bb2, c1 = bb2, c2 = bb2, c3 = bb2;
#pragma unroll 8
    for (int k = 0; k < HID_; ++k) {
        float4 wv = w2t4[(size_t)k * 64 + tc];         // 1KB/wave, coalesced
        float x0 = lh[4 * tb + 0][k];                  // LDS broadcast
        float x1 = lh[4 * tb + 1][k];
        float x2 = lh[4 * tb + 2][k];
        float x3 = lh[4 * tb + 3][k];
        c0.x = fmaf(x0, wv.x, c0.x); c0.y = fmaf(x0, wv.y, c0.y);
        c0.z = fmaf(x0, wv.z, c0.z); c0.w = fmaf(x0, wv.w, c0.w);
        c1.x = fmaf(x1, wv.x, c1.x); c1.y = fmaf(x1, wv.y, c1.y);
        c1.z = fmaf(x1, wv.z, c1.z); c1.w = fmaf(x1, wv.w, c1.w);
        c2.x = fmaf(x2, wv.x, c2.x); c2.y = fmaf(x2, wv.y, c2.y);
        c2.z = fmaf(x2, wv.z, c2.z); c2.w = fmaf(x2, wv.w, c2.w);
        c3.x = fmaf(x3, wv.x, c3.x); c3.y = fmaf(x3, wv.y, c3.y);
        c3.z = fmaf(x3, wv.z, c3.z); c3.w = fmaf(x3, wv.w, c3.w);
    }

    s = 0.f; ss = 0.f;
    {
        float4 cc[4] = {c0, c1, c2, c3};
#pragma unroll
        for (int j = 0; j < 4; ++j) {
            s  += cc[j].x + cc[j].y + cc[j].z + cc[j].w;
            ss += cc[j].x * cc[j].x + cc[j].y * cc[j].y
                + cc[j].z * cc[j].z + cc[j].w * cc[j].w;
        }
    }
#pragma unroll
    for (int o = 32; o > 0; o >>= 1) { s += __shfl_down(s, o); ss += __shfl_down(ss, o); }
    if (l == 0) { rs[w] = s; rss[w] = ss; }   // safe: BN1 rs reads pre-barrier
    __syncthreads();
    S = 0.f; SS = 0.f;
#pragma unroll
    for (int j = 0; j < 8; ++j) { S += rs[j]; SS += rss[j]; }
    mean = S * inv;
    var  = SS * inv - mean * mean;
    float sc2 = g2[g] * rsqrtf(var + EPS_);
    float sh2 = be2[g] - mean * sc2;

    {
        float4 cc[4] = {c0, c1, c2, c3};
#pragma unroll
        for (int j = 0; j < 4; ++j) {
            int b = 4 * tb + j;
            float4 v;
            v.x = fmaxf(fmaf(cc[j].x, sc2, sh2), 0.f);
            v.y = fmaxf(fmaf(cc[j].y, sc2, sh2), 0.f);
            v.z = fmaxf(fmaf(cc[j].z, sc2, sh2), 0.f);
            v.w = fmaxf(fmaf(cc[j].w, sc2, sh2), 0.f);
            z4[(size_t)(b * G_ + g) * 64 + tc] = v;
        }
    }
}

// ---------------------------------------------------------------------------
extern "C" void kernel_launch(void* const* d_in, const int* in_sizes, int n_in,
                              void* d_out, int out_size, void* d_ws, size_t ws_size,
                              hipStream_t stream) {
    const float* x    = (const float*)d_in[0];
    const float* mask = (const float*)d_in[1];
    const float* W1   = (const float*)d_in[2];
    const float* b1   = (const float*)d_in[3];
    const float* g1   = (const float*)d_in[4];
    const float* be1  = (const float*)d_in[5];
    const float* W2   = (const float*)d_in[6];
    const float* b2   = (const float*)d_in[7];
    const float* g2   = (const float*)d_in[8];
    const float* be2  = (const float*)d_in[9];
    float* out = (float*)d_out;

    char* ws = (char*)d_ws;
    size_t off = 0;
    auto take = [&](size_t bytes) {
        char* p = ws + off;
        off = (off + bytes + 255) & ~(size_t)255;
        return p;
    };
    __hip_bfloat16* w1bf = (__hip_bfloat16*)take((size_t)N_ * HID_ * 2);  // (N,HID) bf16
    float* xt            = (float*)take((size_t)N_ * B_ * 4);             // (N,B)
    float* w2t           = (float*)take((size_t)HID_ * HID_ * 4);         // (HID,Z)
    float* hpartS        = (float*)take((size_t)NSPB2_ * B_ * HID_ * 4);  // 33.5MB
    float* hpartD        = (float*)take((size_t)DKB_ * B_ * HID_ * 4);
    float* h255          = (float*)take((size_t)B_ * HID_ * 4);
    int* cnt4            = (int*)take((size_t)G_ * QK_ * 4);
    unsigned short* idx  = (unsigned short*)take((size_t)G_ * QK_ * QCAP_ * 2);

    prep_k<<<PREP_GRID, 256, 0, stream>>>(W1, x, W2, mask, w1bf, xt, w2t,
                                          cnt4, idx);
    spgemm_k<<<K2_GRID, 256, 0, stream>>>((const uint2*)w1bf, (const float4*)xt,
                                          cnt4, idx,
                                          (float4*)hpartS, (float4*)hpartD);
    reduce_k<<<(B_ * HID_) / 256, 256, 0, stream>>>(hpartD, b1, h255);
    fused_k<<<G_, 512, 0, stream>>>((const float4*)hpartS, (const float4*)h255,
                                    (const float4*)w2t, (const float4*)b1,
                                    g1, be1, (const float4*)b2, g2, be2,
                                    (float4*)out);
}

// Round 16
// 61.679 us; speedup vs baseline: 1.5059x; 1.5059x over previous
//
#include <hip/hip_runtime.h>
#include <hip/hip_bf16.h>

#define B_    32
#define N_    10000
#define G_    256
#define HID_  256
#define EPS_  1e-5f

typedef __attribute__((ext_vector_type(8))) short short8_t;
typedef __attribute__((ext_vector_type(4))) float f32x4;

// prep_k grid segmentation
#define TB_W1  2504            // W1 transpose->bf16: 313 x 8 tiles
#define TB_X   313             // x transpose->bf16: 32 x 10000
#define NB_W2C 64              // W2 -> bf16 cast (no transpose)
#define NB_CMP 256             // mask compaction, one block per g
#define PREP_GRID (TB_W1 + TB_X + NB_W2C + NB_CMP + 1)   // 3138 (+1 zero-row)

#define DKB_  40               // dense-group split-K producer blocks
#define DCH_  250              // genes per dense chunk (40*250 = 10000)
#define MEGA_GRID (DKB_ + 255 + 1)   // 296

#define LAP_  264              // LA / lhf pitch in elements (16B-aligned rows)

// ---------------------------------------------------------------------------
// Tiled transpose helpers.
// ---------------------------------------------------------------------------
__device__ inline void transpose_tile_bf16(const float* __restrict__ src,
                                           __hip_bfloat16* __restrict__ dst,
                                           int R, int C, int bx, int by, int t,
                                           float (*tile)[33]) {
    int tx = t & 31, ty = t >> 5;      // 32 x 8
    int c0 = bx * 32, r0 = by * 32;
#pragma unroll
    for (int j = 0; j < 4; ++j) {
        int r = r0 + ty + j * 8, c = c0 + tx;
        if (r < R && c < C) tile[ty + j * 8][tx] = src[(size_t)r * C + c];
    }
    __syncthreads();
#pragma unroll
    for (int j = 0; j < 4; ++j) {
        int c = c0 + ty + j * 8, r = r0 + tx;
        if (r < R && c < C)
            dst[(size_t)c * R + r] = __float2bfloat16(tile[tx][ty + j * 8]);
    }
}

// ---------------------------------------------------------------------------
// Fused prep: W1/x -> bf16 transposes, W2 -> bf16 cast, compaction, zero-row.
// ---------------------------------------------------------------------------
__global__ __launch_bounds__(256) void prep_k(const float* __restrict__ W1,
                                              const float* __restrict__ x,
                                              const float* __restrict__ W2,
                                              const float* __restrict__ mask,
                                              __hip_bfloat16* __restrict__ w1bf,
                                              __hip_bfloat16* __restrict__ xtbf,
                                              __hip_bfloat16* __restrict__ w2bf,
                                              int* __restrict__ cnt,
                                              unsigned short* __restrict__ idx,
                                              int* __restrict__ ctr) {
    __shared__ float tile[32][33];
    __shared__ int c;
    int bid = blockIdx.x, t = threadIdx.x;

    if (bid == 0 && t == 0) *ctr = 0;  // reset mega_k producer counter

    if (bid < TB_W1) {
        transpose_tile_bf16(W1, w1bf, HID_, N_, bid % 313, bid / 313, t, tile);
    } else if (bid < TB_W1 + TB_X) {
        transpose_tile_bf16(x, xtbf, B_, N_, bid - TB_W1, 0, t, tile);
    } else if (bid < TB_W1 + TB_X + NB_W2C) {
        int b = bid - (TB_W1 + TB_X);
#pragma unroll
        for (int j = 0; j < 4; ++j) {
            int i = b * 1024 + j * 256 + t;
            w2bf[i] = __float2bfloat16(W2[i]);
        }
    } else if (bid < TB_W1 + TB_X + NB_W2C + NB_CMP) {
        int g = bid - (TB_W1 + TB_X + NB_W2C);
        if (g == 255) return;              // dense group: contiguous, no list
        if (t == 0) c = 0;
        __syncthreads();
        for (int n = t; n < N_; n += 256) {
            if (mask[(size_t)g * N_ + n] != 0.0f) {
                int p = atomicAdd(&c, 1);          // LDS atomic only
                idx[(size_t)g * N_ + p] = (unsigned short)n;
            }
        }
        __syncthreads();
        if (t == 0) cnt[g] = c;
    } else {
        // zero row N_ of w1bf and xtbf (pad-gene target: contributes 0)
        w1bf[(size_t)N_ * 256 + t] = __float2bfloat16(0.f);
        if (t < 32) xtbf[(size_t)N_ * 32 + t] = __float2bfloat16(0.f);
    }
}

// ---------------------------------------------------------------------------
// MEGA kernel, MFMA + direct-global fragment gather (no phase-A LDS/barriers).
//   bid <  40  : dense producer (group 255, 250 genes) -> hpartD (f32), ctr++
//   bid 40..294: sparse group g = bid-40, fully fused in-block
//   bid == 295 : dense consumer: spin ctr, reduce partials, fused tail
// 512 threads = 8 waves. Wave w owns output cols [w*32, w*32+32) (2 N-tiles)
// x both M-tiles (rows 0..31). Fragments (HW-verified in round 11):
//   A: lane l -> A[l&15][(l>>4)*8+j]       (A[b][k] = x_bf16[gene_k][b])
//   B: lane l -> B[(l>>4)*8+j][l&15]       (B[k][h] = W1_bf16[gene_k][h])
//   C/D: lane l reg r -> D[(l>>4)*4+r][l&15]
// Tail genes map to zero-row N_ (branchless select) -> no remainder code.
// ---------------------------------------------------------------------------
__global__ __launch_bounds__(512, 2) void mega_k(const unsigned short* __restrict__ w1bf,
                                                 const unsigned short* __restrict__ xtbf,
                                                 const int* __restrict__ cnt,
                                                 const unsigned short* __restrict__ idx,
                                                 const float* __restrict__ b1,
                                                 const float* __restrict__ g1,
                                                 const float* __restrict__ be1,
                                                 const unsigned short* __restrict__ w2bf,
                                                 const float* __restrict__ b2,
                                                 const float* __restrict__ g2,
                                                 const float* __restrict__ be2,
                                                 float* __restrict__ hpartD,
                                                 int* __restrict__ ctr,
                                                 float* __restrict__ zout) {
    __shared__ __align__(16) char smem[50688];
    __shared__ float rs[8], rss[8];
    float* lhf         = (float*)smem;                      // [32][264] f32
    unsigned short* LA = (unsigned short*)(smem + 33792);   // [32][264] bf16

    const int t = threadIdx.x, bid = blockIdx.x;
    const int w   = t >> 6;            // wave id -> N cols [w*32, w*32+32)
    const int l   = t & 63;
    const int lm  = l & 15;            // intra-tile m/n index
    const int kg  = l >> 4;            // k-group (0..3)
    const int kg8 = kg * 8;

    const bool producer = (bid < DKB_);
    const bool sparse   = (bid >= DKB_ && bid < DKB_ + 255);
    const int g = sparse ? (bid - DKB_) : 255;

    f32x4 acc[2][2];                   // [mt][nt]
#pragma unroll
    for (int mt = 0; mt < 2; ++mt)
#pragma unroll
        for (int nt = 0; nt < 2; ++nt)
#pragma unroll
            for (int r = 0; r < 4; ++r) acc[mt][nt][r] = 0.f;

    if (producer || sparse) {
        // ========== phase A: GEMM1, direct-global MFMA fragments ==========
        const int k0   = producer ? bid * DCH_ : 0;        // absolute gene base
        const int kend = producer ? DCH_ : cnt[g];         // relative count
        const unsigned short* lp = idx + (size_t)g * N_;

        for (int base = 0; base < kend; base += 32) {
            int nj[8];
            if (sparse) {
                uint4 ip = *(const uint4*)(lp + base + kg8);   // 16B, aligned
                unsigned int uu[4] = {ip.x, ip.y, ip.z, ip.w};
#pragma unroll
                for (int j = 0; j < 8; ++j) {
                    int kk = base + kg8 + j;
                    int nv = (int)((uu[j >> 1] >> ((j & 1) * 16)) & 0xffffu);
                    nj[j] = (kk < kend) ? nv : N_;             // pad -> zero row
                }
            } else {
#pragma unroll
                for (int j = 0; j < 8; ++j) {
                    int kk = base + kg8 + j;
                    nj[j] = (kk < kend) ? (k0 + kk) : N_;
                }
            }
            short8_t af0, af1, bf0, bf1;
#pragma unroll
            for (int j = 0; j < 8; ++j) {
                const int n = nj[j];
                af0[j] = (short)xtbf[(size_t)n * 32 + lm];             // A[b][k]
                af1[j] = (short)xtbf[(size_t)n * 32 + 16 + lm];
                bf0[j] = (short)w1bf[(size_t)n * 256 + w * 32 + lm];   // B[k][h]
                bf1[j] = (short)w1bf[(size_t)n * 256 + w * 32 + 16 + lm];
            }
            acc[0][0] = __builtin_amdgcn_mfma_f32_16x16x32_bf16(af0, bf0, acc[0][0], 0, 0, 0);
            acc[0][1] = __builtin_amdgcn_mfma_f32_16x16x32_bf16(af0, bf1, acc[0][1], 0, 0, 0);
            acc[1][0] = __builtin_amdgcn_mfma_f32_16x16x32_bf16(af1, bf0, acc[1][0], 0, 0, 0);
            acc[1][1] = __builtin_amdgcn_mfma_f32_16x16x32_bf16(af1, bf1, acc[1][1], 0, 0, 0);
        }

        if (producer) {
            // accs -> lhf -> coalesced hpartD
#pragma unroll
            for (int mt = 0; mt < 2; ++mt)
#pragma unroll
                for (int nt = 0; nt < 2; ++nt)
#pragma unroll
                    for (int r = 0; r < 4; ++r)
                        lhf[(mt * 16 + kg * 4 + r) * LAP_ +
                            (w * 32 + nt * 16 + lm)] = acc[mt][nt][r];
            __syncthreads();
#pragma unroll
            for (int it = 0; it < 16; ++it) {
                int id = it * 512 + t;
                hpartD[(size_t)bid * 8192 + id] = lhf[(id >> 8) * LAP_ + (id & 255)];
            }
            __threadfence();
            __syncthreads();
            if (t == 0)
                __hip_atomic_fetch_add(ctr, 1, __ATOMIC_RELEASE,
                                       __HIP_MEMORY_SCOPE_AGENT);
            return;
        }

        // -------- sparse: + b1, BN1 stats from registers --------
        float b1v0 = b1[w * 32 + lm], b1v1 = b1[w * 32 + 16 + lm];
        float s = 0.f, ss = 0.f;
#pragma unroll
        for (int mt = 0; mt < 2; ++mt)
#pragma unroll
            for (int nt = 0; nt < 2; ++nt)
#pragma unroll
                for (int r = 0; r < 4; ++r) {
                    float v = acc[mt][nt][r] + (nt ? b1v1 : b1v0);
                    acc[mt][nt][r] = v;
                    s += v; ss += v * v;
                }
#pragma unroll
        for (int o = 32; o > 0; o >>= 1) { s += __shfl_down(s, o); ss += __shfl_down(ss, o); }
        if (l == 0) { rs[w] = s; rss[w] = ss; }
        __syncthreads();
        float S = 0.f, SS = 0.f;
#pragma unroll
        for (int j = 0; j < 8; ++j) { S += rs[j]; SS += rss[j]; }
        const float inv = 1.0f / (float)(B_ * HID_);
        float mean = S * inv;
        float var  = SS * inv - mean * mean;      // biased, matches jnp.var
        float sc = g1[g] * rsqrtf(var + EPS_);
        float sh = be1[g] - mean * sc;
        // normalize + ReLU -> LA (bf16)
#pragma unroll
        for (int mt = 0; mt < 2; ++mt)
#pragma unroll
            for (int nt = 0; nt < 2; ++nt)
#pragma unroll
                for (int r = 0; r < 4; ++r) {
                    float y = fmaxf(fmaf(acc[mt][nt][r], sc, sh), 0.f);
                    __hip_bfloat16 hb = __float2bfloat16(y);
                    LA[(mt * 16 + kg * 4 + r) * LAP_ + (w * 32 + nt * 16 + lm)] =
                        *reinterpret_cast<unsigned short*>(&hb);
                }
        __syncthreads();
    } else {
        // ================= dense consumer =================
        if (t == 0) {
            while (__hip_atomic_load(ctr, __ATOMIC_ACQUIRE,
                                     __HIP_MEMORY_SCOPE_AGENT) < DKB_)
                __builtin_amdgcn_s_sleep(1);
            __threadfence();
        }
        __syncthreads();
        float s = 0.f, ss = 0.f;
#pragma unroll
        for (int it = 0; it < 16; ++it) {
            int id = it * 512 + t;
            float v = b1[id & 255];
            for (int kb = 0; kb < DKB_; ++kb)
                v += hpartD[(size_t)kb * 8192 + id];
            lhf[(id >> 8) * LAP_ + (id & 255)] = v;
            s += v; ss += v * v;
        }
#pragma unroll
        for (int o = 32; o > 0; o >>= 1) { s += __shfl_down(s, o); ss += __shfl_down(ss, o); }
        if (l == 0) { rs[w] = s; rss[w] = ss; }
        __syncthreads();
        float S = 0.f, SS = 0.f;
#pragma unroll
        for (int j = 0; j < 8; ++j) { S += rs[j]; SS += rss[j]; }
        const float inv = 1.0f / (float)(B_ * HID_);
        float mean = S * inv;
        float var  = SS * inv - mean * mean;
        float sc = g1[255] * rsqrtf(var + EPS_);
        float sh = be1[255] - mean * sc;
#pragma unroll
        for (int it = 0; it < 16; ++it) {
            int id = it * 512 + t;
            float v = lhf[(id >> 8) * LAP_ + (id & 255)];
            float y = fmaxf(fmaf(v, sc, sh), 0.f);
            __hip_bfloat16 hb = __float2bfloat16(y);
            LA[(id >> 8) * LAP_ + (id & 255)] =
                *reinterpret_cast<unsigned short*>(&hb);
        }
        __syncthreads();
    }

    // ================= GEMM2 via MFMA + BN2 + ReLU =================
    f32x4 a2[2][2];
#pragma unroll
    for (int mt = 0; mt < 2; ++mt)
#pragma unroll
        for (int nt = 0; nt < 2; ++nt)
#pragma unroll
            for (int r = 0; r < 4; ++r) a2[mt][nt][r] = 0.f;

#pragma unroll
    for (int ks = 0; ks < 8; ++ks) {
        short8_t af[2], bfm[2];
#pragma unroll
        for (int mt = 0; mt < 2; ++mt)
            af[mt] = *(const short8_t*)&LA[(mt * 16 + lm) * LAP_ + ks * 32 + kg8];
#pragma unroll
        for (int nt = 0; nt < 2; ++nt)
            bfm[nt] = *(const short8_t*)&w2bf[(size_t)(w * 32 + nt * 16 + lm) * 256 +
                                              ks * 32 + kg8];
#pragma unroll
        for (int mt = 0; mt < 2; ++mt)
#pragma unroll
            for (int nt = 0; nt < 2; ++nt)
                a2[mt][nt] = __builtin_amdgcn_mfma_f32_16x16x32_bf16(
                    af[mt], bfm[nt], a2[mt][nt], 0, 0, 0);
    }

    float b2v0 = b2[w * 32 + lm], b2v1 = b2[w * 32 + 16 + lm];
    float s2 = 0.f, ss2 = 0.f;
#pragma unroll
    for (int mt = 0; mt < 2; ++mt)
#pragma unroll
        for (int nt = 0; nt < 2; ++nt)
#pragma unroll
            for (int r = 0; r < 4; ++r) {
                float v = a2[mt][nt][r] + (nt ? b2v1 : b2v0);
                a2[mt][nt][r] = v;
                s2 += v; ss2 += v * v;
            }
#pragma unroll
    for (int o = 32; o > 0; o >>= 1) { s2 += __shfl_down(s2, o); ss2 += __shfl_down(ss2, o); }
    if (l == 0) { rs[w] = s2; rss[w] = ss2; }   // safe: prior rs reads barrier'd
    __syncthreads();
    float S2 = 0.f, SS2 = 0.f;
#pragma unroll
    for (int j = 0; j < 8; ++j) { S2 += rs[j]; SS2 += rss[j]; }
    const float inv = 1.0f / (float)(B_ * HID_);
    float mean2 = S2 * inv;
    float var2  = SS2 * inv - mean2 * mean2;
    float sc2 = g2[g] * rsqrtf(var2 + EPS_);
    float sh2 = be2[g] - mean2 * sc2;

#pragma unroll
    for (int mt = 0; mt < 2; ++mt)
#pragma unroll
        for (int nt = 0; nt < 2; ++nt)
#pragma unroll
            for (int r = 0; r < 4; ++r) {
                int b = mt * 16 + kg * 4 + r;
                int z = w * 32 + nt * 16 + lm;
                zout[((size_t)b * G_ + g) * 256 + z] =
                    fmaxf(fmaf(a2[mt][nt][r], sc2, sh2), 0.f);
            }
}

// ---------------------------------------------------------------------------
extern "C" void kernel_launch(void* const* d_in, const int* in_sizes, int n_in,
                              void* d_out, int out_size, void* d_ws, size_t ws_size,
                              hipStream_t stream) {
    const float* x    = (const float*)d_in[0];
    const float* mask = (const float*)d_in[1];
    const float* W1   = (const float*)d_in[2];
    const float* b1   = (const float*)d_in[3];
    const float* g1   = (const float*)d_in[4];
    const float* be1  = (const float*)d_in[5];
    const float* W2   = (const float*)d_in[6];
    const float* b2   = (const float*)d_in[7];
    const float* g2   = (const float*)d_in[8];
    const float* be2  = (const float*)d_in[9];
    float* out = (float*)d_out;

    char* ws = (char*)d_ws;
    size_t off = 0;
    auto take = [&](size_t bytes) {
        char* p = ws + off;
        off = (off + bytes + 255) & ~(size_t)255;
        return p;
    };
    __hip_bfloat16* w1bf = (__hip_bfloat16*)take((size_t)(N_ + 1) * HID_ * 2); // (N+1,HID)
    __hip_bfloat16* xtbf = (__hip_bfloat16*)take((size_t)(N_ + 1) * B_ * 2);   // (N+1,B)
    __hip_bfloat16* w2bf = (__hip_bfloat16*)take((size_t)HID_ * HID_ * 2);     // (Z,HID)
    float* hpartD        = (float*)take((size_t)DKB_ * B_ * HID_ * 4);
    int* cnt             = (int*)take((size_t)G_ * 4);
    unsigned short* idx  = (unsigned short*)take((size_t)G_ * N_ * 2);
    int* ctr             = (int*)take(256);

    prep_k<<<PREP_GRID, 256, 0, stream>>>(W1, x, W2, mask, w1bf, xtbf, w2bf,
                                          cnt, idx, ctr);
    mega_k<<<MEGA_GRID, 512, 0, stream>>>((const unsigned short*)w1bf,
                                          (const unsigned short*)xtbf,
                                          cnt, idx, b1, g1, be1,
                                          (const unsigned short*)w2bf,
                                          b2, g2, be2,
                                          hpartD, ctr, out);
}